// Round 8
// baseline (1305.124 us; speedup 1.0000x reference)
//
#include <hip/hip_runtime.h>
#include <hip/hip_fp16.h>

typedef _Float16 half8 __attribute__((ext_vector_type(8)));
typedef _Float16 half4v __attribute__((ext_vector_type(4)));
typedef float f32x4 __attribute__((ext_vector_type(4)));

#define T_INS 200

// LDS layout (bytes)
constexpr int WI0O = 0;       // 128 KiB: W_ih[0] as MFMA A-fragments
constexpr int H0O  = 131072;  // 2 x 4096 (parity)
constexpr int H1O  = 139264;  // 2 x 4096
constexpr int XTO  = 147456;  // 2 x 4096 (unused in HOIST)
constexpr int BIO  = 155648;  // float[2][512] gate-interleaved biases
constexpr int SMSZ = 159744;  // 156 KiB

constexpr size_t WSZ_PACK  = 524288;                 // 4 x 128KB frag regions
constexpr size_t Z0_BYTES  = 209715200ull;           // 200*32*8*4*1024
constexpr size_t WSZ_HOIST = WSZ_PACK + Z0_BYTES;    // 210,239,488

// swizzled [batch][k(half)] f16 layout (2-way max bank aliasing on b128)
#define OFF(b, k) (((((b) << 8) | ((k) << 1))) ^ (((b) & 7) << 4))

// counted barrier: wait only deep enough that prior ds_writes (issued before
// the N trailing prefetch reads; DS completes in-order) are visible.
#define BAR_K(n) asm volatile("s_waitcnt lgkmcnt(" #n ")\n\ts_barrier" ::: "memory")
#define SCHED_FENCE() __builtin_amdgcn_sched_barrier(0)

__device__ __forceinline__ float sigm(float x) {
  return __builtin_amdgcn_rcpf(1.0f + __builtin_amdgcn_exp2f(-1.44269504f * x));
}
__device__ __forceinline__ float tanh_f(float x) {
  return 1.0f - 2.0f * __builtin_amdgcn_rcpf(1.0f + __builtin_amdgcn_exp2f(2.88539008f * x));
}
__device__ __forceinline__ half8 cvt_frag(const float* __restrict__ src) {
  f32x4 a = *(const f32x4*)src;
  f32x4 b = *(const f32x4*)(src + 4);
  half8 h;
  h[0] = (_Float16)a[0]; h[1] = (_Float16)a[1]; h[2] = (_Float16)a[2]; h[3] = (_Float16)a[3];
  h[4] = (_Float16)b[0]; h[5] = (_Float16)b[1]; h[6] = (_Float16)b[2]; h[7] = (_Float16)b[3];
  return h;
}
// 8-wave row permutation: gate = r&3, unit = w*16 + (r>>2)*4 + mt
__device__ __forceinline__ int perm_row8(int w, int mt, int r) {
  return (r & 3) * 128 + w * 16 + (r >> 2) * 4 + mt;
}

// Pack into ws: region 0 = W_ih[1], 1 = W_hh[0], 2 = W_hh[1], 3 = W_ih[0].
// Frag F = w*16 + mt*4 + kf; 64 lanes x 16B.
__global__ __launch_bounds__(256) void pack_kernel(const float* __restrict__ W_ih,
                                                   const float* __restrict__ W_hh,
                                                   char* __restrict__ ws) {
  int gid = blockIdx.x * 256 + threadIdx.x;  // 32768 threads exactly
  int G = gid >> 6, lane = gid & 63;
  int region = G >> 7, F = G & 127;
  int w = F >> 4, mt = (F >> 2) & 3, kf = F & 3;
  int row = perm_row8(w, mt, lane & 15);
  int k0 = kf * 32 + (lane >> 4) * 8;
  const float* src;
  if (region == 0)      src = W_ih + (size_t)(512 + row) * 128 + k0;
  else if (region == 3) src = W_ih + (size_t)row * 128 + k0;
  else                  src = W_hh + (size_t)((region - 1) * 512 + row) * 128 + k0;
  *(half8*)(ws + (size_t)G * 1024 + lane * 16) = cvt_frag(src);
}

// Full-chip precompute: Z0[t][bg][w][mt][lane] = bias0 + W_ih[0] @ x(t)
// laid out exactly as the lstm acc fragment (f32x4 per lane per mt).
__global__ __launch_bounds__(512) void zgemm_kernel(const float* __restrict__ x,
                                                    const float* __restrict__ b_ih,
                                                    const float* __restrict__ b_hh,
                                                    char* __restrict__ ws) {
  __shared__ __attribute__((aligned(16))) char sx[4096];
  const int tid = threadIdx.x;
  const int w = tid >> 6, lane = tid & 63;
  const int lb = lane & 15, lg = lane >> 4;
  const int k0b = lg * 8;
  const int u0 = w * 16 + lg * 4;
  const int t = blockIdx.x >> 5, bg = blockIdx.x & 31;

  // stage x[bg tile, t] into LDS (f16, swizzled)
  {
    int b = tid >> 5, k4 = (tid & 31) * 4;
    f32x4 v = *(const f32x4*)(x + ((size_t)(bg * 16 + b) * T_INS + t) * 128 + k4);
    half4v hx;
    hx[0] = (_Float16)v[0]; hx[1] = (_Float16)v[1];
    hx[2] = (_Float16)v[2]; hx[3] = (_Float16)v[3];
    *(half4v*)(sx + OFF(b, k4)) = hx;
  }
  __syncthreads();

  f32x4 acc[4];
#pragma unroll
  for (int mt = 0; mt < 4; ++mt)
#pragma unroll
    for (int q = 0; q < 4; ++q)
      acc[mt][q] = b_ih[q * 128 + u0 + mt] + b_hh[q * 128 + u0 + mt];

  half8 bf[4];
#pragma unroll
  for (int kf = 0; kf < 4; ++kf)
    bf[kf] = *(const half8*)(sx + OFF(lb, kf * 32 + k0b));

  const char* wbase = ws + 393216 + (size_t)lane * 16;  // region 3
#pragma unroll
  for (int kf = 0; kf < 4; ++kf)
#pragma unroll
    for (int mt = 0; mt < 4; ++mt) {
      half8 a = *(const half8*)(wbase + (w * 16 + mt * 4 + kf) * 1024);
      acc[mt] = __builtin_amdgcn_mfma_f32_16x16x32_f16(a, bf[kf], acc[mt], 0, 0, 0);
    }

  char* zp = ws + WSZ_PACK + ((size_t)blockIdx.x * 8 + w) * 4096 + lane * 16;
#pragma unroll
  for (int mt = 0; mt < 4; ++mt)
    *(f32x4*)(zp + mt * 1024) = acc[mt];
}

template <int PACKED, int HOIST>
__global__ __launch_bounds__(512, 2) void lstm_kernel(
    const float* __restrict__ x, const int* __restrict__ len_in,
    const int* __restrict__ len_ar, const float* __restrict__ W_ih,
    const float* __restrict__ W_hh, const float* __restrict__ b_ih,
    const float* __restrict__ b_hh, const char* __restrict__ ws,
    float* __restrict__ out) {
  __shared__ __attribute__((aligned(16))) char sm[SMSZ];
  float* biasS = (float*)(sm + BIO);

  const int tid = threadIdx.x;
  const int w = tid >> 6, lane = tid & 63;
  const int lb = lane & 15, lg = lane >> 4;
  const int k0b = lg * 8;
  const int u0 = w * 16 + lg * 4;  // lane's 4 contiguous units
  const int batch = blockIdx.x * 16 + lb;
  const int Lin = len_in[batch];
  const int Lar = len_ar[batch];

  // ---- one-time init ----
  // W_ih[0] -> LDS as frags (needed for AR phase; also TF when !HOIST)
  for (int j = 0; j < 16; ++j) {
    int pos = tid * 256 + j * 16;
    int F = pos >> 10, ln = (pos >> 4) & 63;
    int fw = F >> 4, fmt = (F >> 2) & 3, fkf = F & 3;
    int row = perm_row8(fw, fmt, ln & 15);
    int k0 = fkf * 32 + (ln >> 4) * 8;
    *(half8*)(sm + WI0O + pos) = cvt_frag(W_ih + (size_t)row * 128 + k0);
  }
  for (int i = tid; i < 1024; i += 512) {
    int l = i >> 9, rp = i & 511, u = rp >> 2, q = rp & 3;
    biasS[i] = b_ih[l * 512 + q * 128 + u] + b_hh[l * 512 + q * 128 + u];
  }
#pragma unroll
  for (int i = 0; i < 2; ++i)
    *(f32x4*)(sm + H0O + tid * 16 + i * 8192) = (f32x4){0.f, 0.f, 0.f, 0.f};

  const int xb = tid >> 5, xk4 = (tid & 31) * 4;
  if (!HOIST) {
    f32x4 v = *(const f32x4*)(x + ((size_t)(blockIdx.x * 16 + xb) * T_INS) * 128 + xk4);
    half4v hx;
    hx[0] = (_Float16)v[0]; hx[1] = (_Float16)v[1];
    hx[2] = (_Float16)v[2]; hx[3] = (_Float16)v[3];
    *(half4v*)(sm + XTO + OFF(xb, xk4)) = hx;
  }

  // resident weights: 48 half8 = 192 regs/wave (AGPR+VGPR)
  half8 whh0[4][4], whh1[4][4], wi1[4][4];
  if (PACKED) {
    const char* base = ws + (size_t)lane * 16;
#pragma unroll
    for (int mt = 0; mt < 4; ++mt)
#pragma unroll
      for (int kf = 0; kf < 4; ++kf) {
        int fo = (w * 16 + mt * 4 + kf) * 1024;
        wi1[mt][kf]  = *(const half8*)(base + fo);
        whh0[mt][kf] = *(const half8*)(base + 131072 + fo);
        whh1[mt][kf] = *(const half8*)(base + 262144 + fo);
      }
  } else {
#pragma unroll
    for (int mt = 0; mt < 4; ++mt)
#pragma unroll
      for (int kf = 0; kf < 4; ++kf) {
        int row = perm_row8(w, mt, lb);
        wi1[mt][kf]  = cvt_frag(W_ih + (size_t)(512 + row) * 128 + kf * 32 + k0b);
        whh0[mt][kf] = cvt_frag(W_hh + (size_t)row * 128 + kf * 32 + k0b);
        whh1[mt][kf] = cvt_frag(W_hh + (size_t)(512 + row) * 128 + kf * 32 + k0b);
      }
  }

  float c0[4], c1[4];
  half4v hp0v, hp1v;
#pragma unroll
  for (int i = 0; i < 4; ++i) {
    c0[i] = c1[i] = 0.f;
    hp0v[i] = (_Float16)0.f; hp1v[i] = (_Float16)0.f;
  }
  __syncthreads();

  const float* xptr = x + ((size_t)(blockIdx.x * 16 + xb) * T_INS + 1) * 128 + xk4;
  float* optr = out + (size_t)batch * 25600 + u0;
  const size_t obase_ar = 13107200ull + (size_t)batch * 25600 + u0;
  const char* wi0base = sm + WI0O + w * 16384 + lane * 16;
  const char* zp = ws + WSZ_PACK + ((size_t)(blockIdx.x * 8 + w)) * 4096 + lane * 16;

  // pre-loop: acc for t=0, bf = h0(-1)=0 fragments (H0O parity 1, zeroed)
  f32x4 acc[4];
  half8 bf[4];
  if (HOIST) {
#pragma unroll
    for (int mt = 0; mt < 4; ++mt) acc[mt] = *(const f32x4*)(zp + mt * 1024);
  } else {
#pragma unroll
    for (int mt = 0; mt < 4; ++mt) acc[mt] = *(const f32x4*)(biasS + (u0 + mt) * 4);
  }
#pragma unroll
  for (int kf = 0; kf < 4; ++kf)
    bf[kf] = *(const half8*)(sm + H0O + 4096 + OFF(lb, kf * 32 + k0b));

  for (int t = 0; t < 400; ++t) {
    const int p = t & 1;
    const bool tf = (t < 200);
    const bool mk = tf ? (t < Lin) : ((t - 200) < Lar);

    f32x4 xpre = (f32x4){0.f, 0.f, 0.f, 0.f};
    if (!HOIST && t < 199) { xpre = *(const f32x4*)xptr; xptr += 128; }

    // ================= layer 0 =================
    // acc preloaded (Z or bias); bf carries h0(t-1) from last step's ih1 read
#pragma unroll
    for (int kf = 0; kf < 4; ++kf)
#pragma unroll
      for (int mt = 0; mt < 4; ++mt)
        acc[mt] = __builtin_amdgcn_mfma_f32_16x16x32_f16(whh0[mt][kf], bf[kf],
                                                         acc[mt], 0, 0, 0);
    if (!HOIST || !tf) {
      // X-operand: TF = x(t) (staged), AR = h1(t-1)
      const char* sX = tf ? (sm + XTO + p * 4096) : (sm + H1O + p * 4096);
#pragma unroll
      for (int kf = 0; kf < 4; ++kf)
        bf[kf] = *(const half8*)(sX + OFF(lb, kf * 32 + k0b));
#pragma unroll
      for (int kf = 0; kf < 4; ++kf)
#pragma unroll
        for (int mt = 0; mt < 4; ++mt) {
          half8 a = *(const half8*)(wi0base + (mt * 4 + kf) * 1024);
          acc[mt] = __builtin_amdgcn_mfma_f32_16x16x32_f16(a, bf[kf], acc[mt], 0, 0, 0);
        }
    }
    // ACT0
    {
      _Float16 h4[4];
#pragma unroll
      for (int mt = 0; mt < 4; ++mt) {
        float si = sigm(acc[mt][0]);
        float sf = sigm(acc[mt][1]);
        float tg = tanh_f(acc[mt][2]);
        float so = sigm(acc[mt][3]);
        float cn = sf * c0[mt] + si * tg;
        float hn = so * tanh_f(cn);
        c0[mt] = mk ? cn : c0[mt];
        h4[mt] = (_Float16)hn;
      }
      hp0v = mk ? *(half4v*)h4 : hp0v;
      *(half4v*)(sm + H0O + p * 4096 + OFF(lb, u0)) = hp0v;
    }
    // prefetch for layer 1 (pinned after the h0 write so lgkm count is exact)
    SCHED_FENCE();
    if (tf) {
      // TF: layer1 H-operand h1(t-1) differs from bf -> prefetch (4 reads)
#pragma unroll
      for (int kf = 0; kf < 4; ++kf)
        bf[kf] = *(const half8*)(sm + H1O + p * 4096 + OFF(lb, kf * 32 + k0b));
    }  // AR: bf already holds h1(t-1) (layer0's X-operand) -- carry
#pragma unroll
    for (int mt = 0; mt < 4; ++mt)
      acc[mt] = *(const f32x4*)(biasS + 512 + (u0 + mt) * 4);
    SCHED_FENCE();
    if (tf) BAR_K(8); else BAR_K(4);  // h0[p] published; vmem stays in flight

    // stage x(t+1) (only non-hoist TF)
    if (!HOIST && t < 199) {
      half4v hx;
      hx[0] = (_Float16)xpre[0]; hx[1] = (_Float16)xpre[1];
      hx[2] = (_Float16)xpre[2]; hx[3] = (_Float16)xpre[3];
      *(half4v*)(sm + XTO + (p ^ 1) * 4096 + OFF(xb, xk4)) = hx;
    }

    // ================= layer 1 =================
#pragma unroll
    for (int kf = 0; kf < 4; ++kf)
#pragma unroll
      for (int mt = 0; mt < 4; ++mt)
        acc[mt] = __builtin_amdgcn_mfma_f32_16x16x32_f16(whh1[mt][kf], bf[kf],
                                                         acc[mt], 0, 0, 0);
    // X-operand: fresh h0(t); KEPT in bf for next step's hh0 (carry)
#pragma unroll
    for (int kf = 0; kf < 4; ++kf)
      bf[kf] = *(const half8*)(sm + H0O + p * 4096 + OFF(lb, kf * 32 + k0b));
#pragma unroll
    for (int kf = 0; kf < 4; ++kf)
#pragma unroll
      for (int mt = 0; mt < 4; ++mt)
        acc[mt] = __builtin_amdgcn_mfma_f32_16x16x32_f16(wi1[mt][kf], bf[kf],
                                                         acc[mt], 0, 0, 0);
    // ACT1 + output
    {
      _Float16 h4[4];
      f32x4 vo;
#pragma unroll
      for (int mt = 0; mt < 4; ++mt) {
        float si = sigm(acc[mt][0]);
        float sf = sigm(acc[mt][1]);
        float tg = tanh_f(acc[mt][2]);
        float so = sigm(acc[mt][3]);
        float cn = sf * c1[mt] + si * tg;
        float hn = so * tanh_f(cn);
        c1[mt] = mk ? cn : c1[mt];
        h4[mt] = (_Float16)hn;
        vo[mt] = mk ? hn : 0.0f;
      }
      hp1v = mk ? *(half4v*)h4 : hp1v;
      *(half4v*)(sm + H1O + (p ^ 1) * 4096 + OFF(lb, u0)) = hp1v;
      *(f32x4*)optr = vo;
      optr += 128;
      if (t == 199) optr = out + obase_ar;
    }
    // preload next step's layer-0 acc (pinned after the h1 write)
    SCHED_FENCE();
    if (HOIST && t + 1 < 200) {
      zp += 1048576;  // 32 blocks * 8 waves * 4096
#pragma unroll
      for (int mt = 0; mt < 4; ++mt) acc[mt] = *(const f32x4*)(zp + mt * 1024);
      SCHED_FENCE();
      BAR_K(0);  // only ds_writes outstanding; Z loads are vmcnt (kept in flight)
    } else {
#pragma unroll
      for (int mt = 0; mt < 4; ++mt) acc[mt] = *(const f32x4*)(biasS + (u0 + mt) * 4);
      SCHED_FENCE();
      BAR_K(4);  // 4 bias reads trail the writes
    }
  }
}

extern "C" void kernel_launch(void* const* d_in, const int* in_sizes, int n_in,
                              void* d_out, int out_size, void* d_ws, size_t ws_size,
                              hipStream_t stream) {
  (void)in_sizes; (void)n_in; (void)out_size;
  const float* x = (const float*)d_in[0];
  const int* len_in = (const int*)d_in[1];
  const int* len_ar = (const int*)d_in[2];
  // d_in[3] = mask_aureg unused (monotone mask recomputed from lengths)
  const float* W_ih = (const float*)d_in[4];
  const float* W_hh = (const float*)d_in[5];
  const float* b_ih = (const float*)d_in[6];
  const float* b_hh = (const float*)d_in[7];
  float* out = (float*)d_out;
  char* ws = (char*)d_ws;

  const bool packed = ws_size >= WSZ_PACK;
  const bool hoist  = ws_size >= WSZ_HOIST;

  if (packed) pack_kernel<<<dim3(128), dim3(256), 0, stream>>>(W_ih, W_hh, ws);
  if (hoist)  zgemm_kernel<<<dim3(6400), dim3(512), 0, stream>>>(x, b_ih, b_hh, ws);

  if (hoist)
    lstm_kernel<1, 1><<<dim3(32), dim3(512), 0, stream>>>(x, len_in, len_ar, W_ih,
                                                          W_hh, b_ih, b_hh, ws, out);
  else if (packed)
    lstm_kernel<1, 0><<<dim3(32), dim3(512), 0, stream>>>(x, len_in, len_ar, W_ih,
                                                          W_hh, b_ih, b_hh, ws, out);
  else
    lstm_kernel<0, 0><<<dim3(32), dim3(512), 0, stream>>>(x, len_in, len_ar, W_ih,
                                                          W_hh, b_ih, b_hh, ws, out);
}